// Round 1
// baseline (1751.757 us; speedup 1.0000x reference)
//
#include <hip/hip_runtime.h>
#include <hip/hip_bf16.h>

#define B_   2
#define N_   2048
#define D_   1024
#define H_   16
#define HD   64
#define HALF 32
#define M_   (B_*N_)     // 4096
#define DQKV (3*D_)      // 3072

// ---------------------------------------------------------------- helpers
__device__ inline float2 upk(unsigned u) {
    // two packed bf16 -> two f32 (bf16 = high 16 bits of f32)
    float2 r;
    r.x = __uint_as_float(u << 16);
    r.y = __uint_as_float(u & 0xffff0000u);
    return r;
}

// ---------------------------------------------------------------- K0: rope tables
__global__ __launch_bounds__(256) void k_tables(float* __restrict__ cos_t,
                                                float* __restrict__ sin_t) {
    int i = blockIdx.x * 256 + threadIdx.x;          // N_*HALF = 65536
    if (i >= N_ * HALF) return;
    int n = i / HALF, j = i % HALF;
    float theta = powf(10000.f, -(float)j / (float)HALF);
    float ang = (float)n * theta;
    cos_t[i] = cosf(ang);
    sin_t[i] = sinf(ang);
}

// ---------------------------------------------------------------- K1: QKV GEMM + elu+1 + rope
// C[m][c] = x[m][:] . w_qkv[:][c] + b_qkv[c];  m = b*N+n, c in [0,3072)
// epilogue writes qf,kf,rq,rk,vv in (B,H,N,64) bf16 layout
__global__ __launch_bounds__(256) void k_qkv(
        const float* __restrict__ x, const float* __restrict__ w,
        const float* __restrict__ bias,
        const float* __restrict__ cos_t, const float* __restrict__ sin_t,
        __hip_bfloat16* __restrict__ qf, __hip_bfloat16* __restrict__ kf,
        __hip_bfloat16* __restrict__ rq, __hip_bfloat16* __restrict__ rk,
        __hip_bfloat16* __restrict__ vv) {
    __shared__ float As[16][64];   // [k][m]
    __shared__ float Bs[16][64];   // [k][n]
    const int t = threadIdx.x;
    const int m0 = blockIdx.y * 64;
    const int n0 = blockIdx.x * 64;
    const int tm = (t & 15) * 4;
    const int tn = (t >> 4) * 4;
    float acc[4][4] = {};

    for (int k0 = 0; k0 < D_; k0 += 16) {
        // A tile: 64 rows x 16 k, one float4/thread, stored transposed
        {
            int row = t >> 2;
            int c4  = (t & 3) * 4;
            const float4 av = *(const float4*)(x + (size_t)(m0 + row) * D_ + k0 + c4);
            As[c4 + 0][row] = av.x; As[c4 + 1][row] = av.y;
            As[c4 + 2][row] = av.z; As[c4 + 3][row] = av.w;
            int krow = t >> 4;
            int nc   = (t & 15) * 4;
            *(float4*)&Bs[krow][nc] =
                *(const float4*)(w + (size_t)(k0 + krow) * DQKV + n0 + nc);
        }
        __syncthreads();
#pragma unroll
        for (int k = 0; k < 16; ++k) {
            float4 a = *(const float4*)&As[k][tm];
            float4 b = *(const float4*)&Bs[k][tn];
            acc[0][0] += a.x*b.x; acc[0][1] += a.x*b.y; acc[0][2] += a.x*b.z; acc[0][3] += a.x*b.w;
            acc[1][0] += a.y*b.x; acc[1][1] += a.y*b.y; acc[1][2] += a.y*b.z; acc[1][3] += a.y*b.w;
            acc[2][0] += a.z*b.x; acc[2][1] += a.z*b.y; acc[2][2] += a.z*b.z; acc[2][3] += a.z*b.w;
            acc[3][0] += a.w*b.x; acc[3][1] += a.w*b.y; acc[3][2] += a.w*b.z; acc[3][3] += a.w*b.w;
        }
        __syncthreads();
    }

    // epilogue: bias, section split, elu+1, rope (pairs are adjacent cols; tn%4==0 so j={0,2} are full pairs)
#pragma unroll
    for (int i = 0; i < 4; ++i) {
        int r = m0 + tm + i;
        int b = r >> 11;            // / N_
        int n = r & (N_ - 1);
#pragma unroll
        for (int j = 0; j < 4; j += 2) {
            int c = n0 + tn + j;
            float v0 = acc[i][j]     + bias[c];
            float v1 = acc[i][j + 1] + bias[c + 1];
            int sec = c >> 10;      // 0=q 1=k 2=v
            int cc  = c & 1023;
            int h = cc >> 6, dd = cc & 63;
            size_t o = ((size_t)(b * H_ + h) * N_ + n) * HD + dd;
            if (sec == 2) {
                vv[o]     = __float2bfloat16(v0);
                vv[o + 1] = __float2bfloat16(v1);
            } else {
                float e0 = v0 > 0.f ? v0 + 1.f : __expf(v0);   // elu(x)+1
                float e1 = v1 > 0.f ? v1 + 1.f : __expf(v1);
                int pj = dd >> 1;
                float cs = cos_t[n * HALF + pj];
                float sn = sin_t[n * HALF + pj];
                float r0 = e0 * cs - e1 * sn;
                float r1 = e0 * sn + e1 * cs;
                if (sec == 0) {
                    qf[o] = __float2bfloat16(e0); qf[o + 1] = __float2bfloat16(e1);
                    rq[o] = __float2bfloat16(r0); rq[o + 1] = __float2bfloat16(r1);
                } else {
                    kf[o] = __float2bfloat16(e0); kf[o + 1] = __float2bfloat16(e1);
                    rk[o] = __float2bfloat16(r0); rk[o + 1] = __float2bfloat16(r1);
                }
            }
        }
    }
}

// ---------------------------------------------------------------- K2: fused linear attention
// per (b,h), q-tile of 64: loop k-tiles of 64:
//   num = rq.rk^T, den = qf.kf^T, w = num/den, o += w @ v
__global__ __launch_bounds__(256) void k_attn(
        const __hip_bfloat16* __restrict__ qf, const __hip_bfloat16* __restrict__ kf,
        const __hip_bfloat16* __restrict__ rq, const __hip_bfloat16* __restrict__ rk,
        const __hip_bfloat16* __restrict__ vv, float* __restrict__ ctx) {
    // transposed pair-packed tiles: [d2][seq], each unsigned = (bf16 d=2*d2, d=2*d2+1)
    __shared__ unsigned sQr[32][64];
    __shared__ unsigned sQe[32][64];
    __shared__ unsigned sKr[32][64];
    __shared__ unsigned sKe[32][64];
    __shared__ __hip_bfloat16 sV[64][64];   // [k][dv] row-major
    __shared__ float sW[64][65];            // [q][k], +1 pad

    const int t  = threadIdx.x;
    const int bh = blockIdx.y;
    const int q0 = blockIdx.x * 64;
    const size_t base = (size_t)bh * (N_ * HD);
    const int tm = (t & 15) * 4;            // q rows
    const int tn = (t >> 4) * 4;            // k cols (gemm1) / dv (pv)

    // stage Q tiles (transpose into pair-packed layout)
    {
        const uint4* gr = (const uint4*)(rq + base + (size_t)q0 * HD);
        const uint4* ge = (const uint4*)(qf + base + (size_t)q0 * HD);
        for (int c = t; c < 512; c += 256) {
            int row = c >> 3;
            int d2  = (c & 7) * 4;
            uint4 a = gr[c], b = ge[c];
            sQr[d2][row] = a.x; sQr[d2+1][row] = a.y; sQr[d2+2][row] = a.z; sQr[d2+3][row] = a.w;
            sQe[d2][row] = b.x; sQe[d2+1][row] = b.y; sQe[d2+2][row] = b.z; sQe[d2+3][row] = b.w;
        }
    }

    float o[4][4] = {};
    for (int kt = 0; kt < 32; ++kt) {
        const int k0 = kt * 64;
        __syncthreads();   // prev PV done (and first-iter Q-stage ordering is covered below)
        {
            const uint4* gr = (const uint4*)(rk + base + (size_t)k0 * HD);
            const uint4* ge = (const uint4*)(kf + base + (size_t)k0 * HD);
            const uint4* gv = (const uint4*)(vv + base + (size_t)k0 * HD);
            for (int c = t; c < 512; c += 256) {
                int row = c >> 3;
                int d2  = (c & 7) * 4;
                uint4 a = gr[c], b = ge[c], vx = gv[c];
                sKr[d2][row] = a.x; sKr[d2+1][row] = a.y; sKr[d2+2][row] = a.z; sKr[d2+3][row] = a.w;
                sKe[d2][row] = b.x; sKe[d2+1][row] = b.y; sKe[d2+2][row] = b.z; sKe[d2+3][row] = b.w;
                *(uint4*)&sV[row][d2 * 2] = vx;
            }
        }
        __syncthreads();

        float num[4][4] = {}, den[4][4] = {};
#pragma unroll 4
        for (int d2 = 0; d2 < 32; ++d2) {
            float2 ar[4], ae[4], br[4], be[4];
#pragma unroll
            for (int i = 0; i < 4; ++i) {
                ar[i] = upk(sQr[d2][tm + i]);
                ae[i] = upk(sQe[d2][tm + i]);
                br[i] = upk(sKr[d2][tn + i]);
                be[i] = upk(sKe[d2][tn + i]);
            }
#pragma unroll
            for (int i = 0; i < 4; ++i)
#pragma unroll
                for (int j = 0; j < 4; ++j) {
                    num[i][j] += ar[i].x * br[j].x + ar[i].y * br[j].y;
                    den[i][j] += ae[i].x * be[j].x + ae[i].y * be[j].y;
                }
        }
#pragma unroll
        for (int i = 0; i < 4; ++i)
#pragma unroll
            for (int j = 0; j < 4; ++j)
                sW[tm + i][tn + j] = num[i][j] / den[i][j];
        __syncthreads();

        // PV: o[q][dv] += sum_k w[q][k] * v[k][dv]
#pragma unroll 8
        for (int kk = 0; kk < 64; ++kk) {
            float a0 = sW[tm + 0][kk], a1 = sW[tm + 1][kk];
            float a2 = sW[tm + 2][kk], a3 = sW[tm + 3][kk];
            uint2 vu = *(const uint2*)&sV[kk][tn];
            float2 v01 = upk(vu.x), v23 = upk(vu.y);
            o[0][0] += a0*v01.x; o[0][1] += a0*v01.y; o[0][2] += a0*v23.x; o[0][3] += a0*v23.y;
            o[1][0] += a1*v01.x; o[1][1] += a1*v01.y; o[1][2] += a1*v23.x; o[1][3] += a1*v23.y;
            o[2][0] += a2*v01.x; o[2][1] += a2*v01.y; o[2][2] += a2*v23.x; o[2][3] += a2*v23.y;
            o[3][0] += a3*v01.x; o[3][1] += a3*v01.y; o[3][2] += a3*v23.x; o[3][3] += a3*v23.y;
        }
    }

#pragma unroll
    for (int i = 0; i < 4; ++i)
#pragma unroll
        for (int j = 0; j < 4; ++j)
            ctx[base + (size_t)(q0 + tm + i) * HD + tn + j] = o[i][j];
}

// ---------------------------------------------------------------- K3: out projection
// out[m][c] = ctx_heads[m][:] . w_out[:][c] + b_out[c]
// ctx is (B,H,N,64); logical A[m][k]: m=b*N+n, k=h*64+dd
__global__ __launch_bounds__(256) void k_proj(
        const float* __restrict__ ctx, const float* __restrict__ w,
        const float* __restrict__ bias, float* __restrict__ out) {
    __shared__ float As[16][64];
    __shared__ float Bs[16][64];
    const int t = threadIdx.x;
    const int m0 = blockIdx.y * 64;
    const int n0 = blockIdx.x * 64;
    const int tm = (t & 15) * 4;
    const int tn = (t >> 4) * 4;
    float acc[4][4] = {};

    for (int k0 = 0; k0 < D_; k0 += 16) {
        {
            int row = t >> 2;
            int c4  = (t & 3) * 4;
            int kk  = k0 + c4;              // 4-aligned, within one head
            int m = m0 + row;
            int b = m >> 11;
            int n = m & (N_ - 1);
            int h = kk >> 6, dd = kk & 63;
            const float4 av = *(const float4*)(ctx + ((size_t)(b * H_ + h) * N_ + n) * HD + dd);
            As[c4 + 0][row] = av.x; As[c4 + 1][row] = av.y;
            As[c4 + 2][row] = av.z; As[c4 + 3][row] = av.w;
            int krow = t >> 4;
            int nc   = (t & 15) * 4;
            *(float4*)&Bs[krow][nc] =
                *(const float4*)(w + (size_t)(k0 + krow) * D_ + n0 + nc);
        }
        __syncthreads();
#pragma unroll
        for (int k = 0; k < 16; ++k) {
            float4 a = *(const float4*)&As[k][tm];
            float4 b = *(const float4*)&Bs[k][tn];
            acc[0][0] += a.x*b.x; acc[0][1] += a.x*b.y; acc[0][2] += a.x*b.z; acc[0][3] += a.x*b.w;
            acc[1][0] += a.y*b.x; acc[1][1] += a.y*b.y; acc[1][2] += a.y*b.z; acc[1][3] += a.y*b.w;
            acc[2][0] += a.z*b.x; acc[2][1] += a.z*b.y; acc[2][2] += a.z*b.z; acc[2][3] += a.z*b.w;
            acc[3][0] += a.w*b.x; acc[3][1] += a.w*b.y; acc[3][2] += a.w*b.z; acc[3][3] += a.w*b.w;
        }
        __syncthreads();
    }

#pragma unroll
    for (int i = 0; i < 4; ++i) {
        int r = m0 + tm + i;
#pragma unroll
        for (int j = 0; j < 4; ++j) {
            int c = n0 + tn + j;
            out[(size_t)r * D_ + c] = acc[i][j] + bias[c];
        }
    }
}

// ---------------------------------------------------------------- launch
extern "C" void kernel_launch(void* const* d_in, const int* in_sizes, int n_in,
                              void* d_out, int out_size, void* d_ws, size_t ws_size,
                              hipStream_t stream) {
    const float* x     = (const float*)d_in[0];
    const float* w_qkv = (const float*)d_in[1];
    const float* b_qkv = (const float*)d_in[2];
    const float* w_out = (const float*)d_in[3];
    const float* b_out = (const float*)d_in[4];
    float* out = (float*)d_out;

    char* ws = (char*)d_ws;
    const size_t TAB   = (size_t)N_ * HALF * sizeof(float);      // 256 KB each
    const size_t HARR  = (size_t)B_ * H_ * N_ * HD * 2;          // 8 MB bf16 each
    float* cos_t = (float*)ws;
    float* sin_t = (float*)(ws + TAB);
    __hip_bfloat16* qf = (__hip_bfloat16*)(ws + 2 * TAB);
    __hip_bfloat16* kf = (__hip_bfloat16*)(ws + 2 * TAB + 1 * HARR);
    __hip_bfloat16* rq = (__hip_bfloat16*)(ws + 2 * TAB + 2 * HARR);
    __hip_bfloat16* rk = (__hip_bfloat16*)(ws + 2 * TAB + 3 * HARR);
    __hip_bfloat16* vv = (__hip_bfloat16*)(ws + 2 * TAB + 4 * HARR);
    float* ctx = (float*)(ws + 2 * TAB + 5 * HARR);              // 16 MB fp32

    hipLaunchKernelGGL(k_tables, dim3((N_ * HALF + 255) / 256), dim3(256), 0, stream,
                       cos_t, sin_t);
    hipLaunchKernelGGL(k_qkv, dim3(DQKV / 64, M_ / 64), dim3(256), 0, stream,
                       x, w_qkv, b_qkv, cos_t, sin_t, qf, kf, rq, rk, vv);
    hipLaunchKernelGGL(k_attn, dim3(N_ / 64, B_ * H_), dim3(256), 0, stream,
                       qf, kf, rq, rk, vv, ctx);
    hipLaunchKernelGGL(k_proj, dim3(D_ / 64, M_ / 64), dim3(256), 0, stream,
                       ctx, w_out, b_out, out);
}

// Round 2
// 566.913 us; speedup vs baseline: 3.0900x; 3.0900x over previous
//
#include <hip/hip_runtime.h>
#include <hip/hip_bf16.h>

#define B_   2
#define N_   2048
#define D_   1024
#define H_   16
#define HD   64
#define HALF 32
#define M_   (B_*N_)     // 4096
#define DQKV (3*D_)      // 3072

typedef __bf16 bf16x8 __attribute__((ext_vector_type(8)));
typedef float  f32x4  __attribute__((ext_vector_type(4)));

// ---------------------------------------------------------------- helpers
__device__ inline float2 upk(unsigned u) {
    float2 r;
    r.x = __uint_as_float(u << 16);
    r.y = __uint_as_float(u & 0xffff0000u);
    return r;
}

// swizzled LDS tile: 64 rows x 64 bf16 (128B = 8 chunks of 16B per row)
// element (row, col): byte = row*128 + ((col>>3) ^ (row&7))*16 + (col&7)*2
__device__ inline bf16x8 ldfrag(const char* tile, int row, int ch) {
    return *(const bf16x8*)(tile + row * 128 + (((ch) ^ (row & 7)) << 4));
}
__device__ inline void stfrag16(char* tile, int row, int ch, uint4 v) {
    *(uint4*)(tile + row * 128 + (((ch) ^ (row & 7)) << 4)) = v;
}

// ---------------------------------------------------------------- K0: rope tables
__global__ __launch_bounds__(256) void k_tables(float* __restrict__ cos_t,
                                                float* __restrict__ sin_t) {
    int i = blockIdx.x * 256 + threadIdx.x;          // N_*HALF = 65536
    if (i >= N_ * HALF) return;
    int n = i / HALF, j = i % HALF;
    float theta = powf(10000.f, -(float)j / (float)HALF);
    float ang = (float)n * theta;
    cos_t[i] = cosf(ang);
    sin_t[i] = sinf(ang);
}

// ---------------------------------------------------------------- K1: QKV GEMM + elu+1 + rope
// qf,kf,rq,rk in (B,H,N,64); vt in (B,H,64,N) (transposed for PV B-frags)
__global__ __launch_bounds__(256) void k_qkv(
        const float* __restrict__ x, const float* __restrict__ w,
        const float* __restrict__ bias,
        const float* __restrict__ cos_t, const float* __restrict__ sin_t,
        __hip_bfloat16* __restrict__ qf, __hip_bfloat16* __restrict__ kf,
        __hip_bfloat16* __restrict__ rq, __hip_bfloat16* __restrict__ rk,
        __hip_bfloat16* __restrict__ vt) {
    __shared__ float As[16][64];   // [k][m]
    __shared__ float Bs[16][64];   // [k][n]
    const int t = threadIdx.x;
    const int m0 = blockIdx.y * 64;
    const int n0 = blockIdx.x * 64;
    const int tm = (t & 15) * 4;
    const int tn = (t >> 4) * 4;
    float acc[4][4] = {};

    for (int k0 = 0; k0 < D_; k0 += 16) {
        {
            int row = t >> 2;
            int c4  = (t & 3) * 4;
            const float4 av = *(const float4*)(x + (size_t)(m0 + row) * D_ + k0 + c4);
            As[c4 + 0][row] = av.x; As[c4 + 1][row] = av.y;
            As[c4 + 2][row] = av.z; As[c4 + 3][row] = av.w;
            int krow = t >> 4;
            int nc   = (t & 15) * 4;
            *(float4*)&Bs[krow][nc] =
                *(const float4*)(w + (size_t)(k0 + krow) * DQKV + n0 + nc);
        }
        __syncthreads();
#pragma unroll
        for (int k = 0; k < 16; ++k) {
            float4 a = *(const float4*)&As[k][tm];
            float4 b = *(const float4*)&Bs[k][tn];
            acc[0][0] += a.x*b.x; acc[0][1] += a.x*b.y; acc[0][2] += a.x*b.z; acc[0][3] += a.x*b.w;
            acc[1][0] += a.y*b.x; acc[1][1] += a.y*b.y; acc[1][2] += a.y*b.z; acc[1][3] += a.y*b.w;
            acc[2][0] += a.z*b.x; acc[2][1] += a.z*b.y; acc[2][2] += a.z*b.z; acc[2][3] += a.z*b.w;
            acc[3][0] += a.w*b.x; acc[3][1] += a.w*b.y; acc[3][2] += a.w*b.z; acc[3][3] += a.w*b.w;
        }
        __syncthreads();
    }

#pragma unroll
    for (int i = 0; i < 4; ++i) {
        int r = m0 + tm + i;
        int b = r >> 11;            // / N_
        int n = r & (N_ - 1);
#pragma unroll
        for (int j = 0; j < 4; j += 2) {
            int c = n0 + tn + j;
            float v0 = acc[i][j]     + bias[c];
            float v1 = acc[i][j + 1] + bias[c + 1];
            int sec = c >> 10;      // 0=q 1=k 2=v
            int cc  = c & 1023;
            int h = cc >> 6, dd = cc & 63;
            if (sec == 2) {
                size_t ov = ((size_t)(b * H_ + h) * HD + dd) * N_ + n;
                vt[ov]      = __float2bfloat16(v0);
                vt[ov + N_] = __float2bfloat16(v1);
            } else {
                size_t o = ((size_t)(b * H_ + h) * N_ + n) * HD + dd;
                float e0 = v0 > 0.f ? v0 + 1.f : __expf(v0);   // elu(x)+1
                float e1 = v1 > 0.f ? v1 + 1.f : __expf(v1);
                int pj = dd >> 1;
                float cs = cos_t[n * HALF + pj];
                float sn = sin_t[n * HALF + pj];
                float r0 = e0 * cs - e1 * sn;
                float r1 = e0 * sn + e1 * cs;
                if (sec == 0) {
                    qf[o] = __float2bfloat16(e0); qf[o + 1] = __float2bfloat16(e1);
                    rq[o] = __float2bfloat16(r0); rq[o + 1] = __float2bfloat16(r1);
                } else {
                    kf[o] = __float2bfloat16(e0); kf[o + 1] = __float2bfloat16(e1);
                    rk[o] = __float2bfloat16(r0); rk[o + 1] = __float2bfloat16(r1);
                }
            }
        }
    }
}

// ---------------------------------------------------------------- K2: fused linear attention (MFMA)
// per (b,h, 64-q-tile): loop 64-k-tiles:
//   num = rq.rk^T, den = qf.kf^T (16 mfma/wave), w = num*rcp(den) -> bf16 sW,
//   o += w @ v (8 mfma/wave).  4 waves, wave w owns q rows w*16..w*16+15.
__global__ __launch_bounds__(256) void k_attn(
        const __hip_bfloat16* __restrict__ qf, const __hip_bfloat16* __restrict__ kf,
        const __hip_bfloat16* __restrict__ rq, const __hip_bfloat16* __restrict__ rk,
        const __hip_bfloat16* __restrict__ vt, float* __restrict__ ctx) {
    __shared__ __align__(16) char sRq[8192];
    __shared__ __align__(16) char sQe[8192];
    __shared__ __align__(16) char sRk[8192];
    __shared__ __align__(16) char sKe[8192];
    __shared__ __align__(16) char sVt[8192];   // rows = dv, cols = k
    __shared__ __align__(16) char sW [8192];   // rows = q,  cols = k (per-wave private slices)

    const int t = threadIdx.x;
    // XCD-chunked swizzle: 1024 blocks, 8 XCDs -> each XCD gets 4 consecutive bh
    const int bid = blockIdx.x;
    const int swz = (bid & 7) * 128 + (bid >> 3);
    const int bh = swz >> 5;          // 0..31
    const int q0 = (swz & 31) * 64;
    const size_t base  = (size_t)bh * (N_ * HD);   // also vt base (HD*N == N*HD)

    const int lane = t & 63;
    const int lrow = lane & 15;
    const int lgrp = lane >> 4;
    const int wid  = t >> 6;
    const int wq0  = wid * 16;

    // ---- stage Q tiles (row-major, swizzled chunks)
    {
        const uint4* gr = (const uint4*)(rq + base + (size_t)q0 * HD);
        const uint4* ge = (const uint4*)(qf + base + (size_t)q0 * HD);
        for (int c = t; c < 512; c += 256) {
            int row = c >> 3, ch = c & 7;
            stfrag16(sRq, row, ch, gr[c]);
            stfrag16(sQe, row, ch, ge[c]);
        }
    }
    __syncthreads();

    // hoisted Q fragments (loop-invariant): A[m][k], m = lane&15, k = (lane>>4)*8+j
    const bf16x8 aqr0 = ldfrag(sRq, wq0 + lrow, lgrp);
    const bf16x8 aqr1 = ldfrag(sRq, wq0 + lrow, 4 + lgrp);
    const bf16x8 aqe0 = ldfrag(sQe, wq0 + lrow, lgrp);
    const bf16x8 aqe1 = ldfrag(sQe, wq0 + lrow, 4 + lgrp);

    f32x4 o[4] = {{0,0,0,0},{0,0,0,0},{0,0,0,0},{0,0,0,0}};

    for (int kt = 0; kt < 32; ++kt) {
        const int k0 = kt * 64;
        __syncthreads();   // previous PV reads of sRk/sKe/sVt done
        {
            const uint4* gr = (const uint4*)(rk + base + (size_t)k0 * HD);
            const uint4* ge = (const uint4*)(kf + base + (size_t)k0 * HD);
            const __hip_bfloat16* gv = vt + base + k0;   // row stride N_
            for (int c = t; c < 512; c += 256) {
                int row = c >> 3, ch = c & 7;
                stfrag16(sRk, row, ch, gr[c]);
                stfrag16(sKe, row, ch, ge[c]);
                uint4 vv = *(const uint4*)(gv + (size_t)row * N_ + ch * 8);
                stfrag16(sVt, row, ch, vv);
            }
        }
        __syncthreads();

        // QK^T: num/den 16x16 fragments, 4 col-frags x 2 k-chunks each
#pragma unroll
        for (int c = 0; c < 4; ++c) {
            f32x4 num = {0,0,0,0}, den = {0,0,0,0};
            bf16x8 brk0 = ldfrag(sRk, c * 16 + lrow, lgrp);
            bf16x8 brk1 = ldfrag(sRk, c * 16 + lrow, 4 + lgrp);
            bf16x8 bke0 = ldfrag(sKe, c * 16 + lrow, lgrp);
            bf16x8 bke1 = ldfrag(sKe, c * 16 + lrow, 4 + lgrp);
            num = __builtin_amdgcn_mfma_f32_16x16x32_bf16(aqr0, brk0, num, 0, 0, 0);
            num = __builtin_amdgcn_mfma_f32_16x16x32_bf16(aqr1, brk1, num, 0, 0, 0);
            den = __builtin_amdgcn_mfma_f32_16x16x32_bf16(aqe0, bke0, den, 0, 0, 0);
            den = __builtin_amdgcn_mfma_f32_16x16x32_bf16(aqe1, bke1, den, 0, 0, 0);
            // w = num/den -> bf16 -> sW (D-frag: row=(lane>>4)*4+r, col=lane&15)
#pragma unroll
            for (int r = 0; r < 4; ++r) {
                float wv = num[r] * __builtin_amdgcn_rcpf(den[r]);
                int row = wq0 + lgrp * 4 + r;
                int col = c * 16 + lrow;
                *(__hip_bfloat16*)(sW + row * 128 + (((col >> 3) ^ (row & 7)) << 4)
                                   + (col & 7) * 2) = __float2bfloat16(wv);
            }
        }

        // PV: o[q][dv] += w @ v ; sW slice is wave-private (lgkmcnt orders write->read)
        bf16x8 aw0 = ldfrag(sW, wq0 + lrow, lgrp);
        bf16x8 aw1 = ldfrag(sW, wq0 + lrow, 4 + lgrp);
#pragma unroll
        for (int f = 0; f < 4; ++f) {
            bf16x8 bv0 = ldfrag(sVt, f * 16 + lrow, lgrp);
            bf16x8 bv1 = ldfrag(sVt, f * 16 + lrow, 4 + lgrp);
            o[f] = __builtin_amdgcn_mfma_f32_16x16x32_bf16(aw0, bv0, o[f], 0, 0, 0);
            o[f] = __builtin_amdgcn_mfma_f32_16x16x32_bf16(aw1, bv1, o[f], 0, 0, 0);
        }
    }

    // epilogue: D-frag row=(lane>>4)*4+r, col=lane&15
#pragma unroll
    for (int f = 0; f < 4; ++f)
#pragma unroll
        for (int r = 0; r < 4; ++r)
            ctx[base + (size_t)(q0 + wq0 + lgrp * 4 + r) * HD + f * 16 + lrow] = o[f][r];
}

// ---------------------------------------------------------------- K3: out projection
__global__ __launch_bounds__(256) void k_proj(
        const float* __restrict__ ctx, const float* __restrict__ w,
        const float* __restrict__ bias, float* __restrict__ out) {
    __shared__ float As[16][64];
    __shared__ float Bs[16][64];
    const int t = threadIdx.x;
    const int m0 = blockIdx.y * 64;
    const int n0 = blockIdx.x * 64;
    const int tm = (t & 15) * 4;
    const int tn = (t >> 4) * 4;
    float acc[4][4] = {};

    for (int k0 = 0; k0 < D_; k0 += 16) {
        {
            int row = t >> 2;
            int c4  = (t & 3) * 4;
            int kk  = k0 + c4;              // within one head
            int m = m0 + row;
            int b = m >> 11;
            int n = m & (N_ - 1);
            int h = kk >> 6, dd = kk & 63;
            const float4 av = *(const float4*)(ctx + ((size_t)(b * H_ + h) * N_ + n) * HD + dd);
            As[c4 + 0][row] = av.x; As[c4 + 1][row] = av.y;
            As[c4 + 2][row] = av.z; As[c4 + 3][row] = av.w;
            int krow = t >> 4;
            int nc   = (t & 15) * 4;
            *(float4*)&Bs[krow][nc] =
                *(const float4*)(w + (size_t)(k0 + krow) * D_ + n0 + nc);
        }
        __syncthreads();
#pragma unroll
        for (int k = 0; k < 16; ++k) {
            float4 a = *(const float4*)&As[k][tm];
            float4 b = *(const float4*)&Bs[k][tn];
            acc[0][0] += a.x*b.x; acc[0][1] += a.x*b.y; acc[0][2] += a.x*b.z; acc[0][3] += a.x*b.w;
            acc[1][0] += a.y*b.x; acc[1][1] += a.y*b.y; acc[1][2] += a.y*b.z; acc[1][3] += a.y*b.w;
            acc[2][0] += a.z*b.x; acc[2][1] += a.z*b.y; acc[2][2] += a.z*b.z; acc[2][3] += a.z*b.w;
            acc[3][0] += a.w*b.x; acc[3][1] += a.w*b.y; acc[3][2] += a.w*b.z; acc[3][3] += a.w*b.w;
        }
        __syncthreads();
    }

#pragma unroll
    for (int i = 0; i < 4; ++i) {
        int r = m0 + tm + i;
#pragma unroll
        for (int j = 0; j < 4; ++j) {
            int c = n0 + tn + j;
            out[(size_t)r * D_ + c] = acc[i][j] + bias[c];
        }
    }
}

// ---------------------------------------------------------------- launch
extern "C" void kernel_launch(void* const* d_in, const int* in_sizes, int n_in,
                              void* d_out, int out_size, void* d_ws, size_t ws_size,
                              hipStream_t stream) {
    const float* x     = (const float*)d_in[0];
    const float* w_qkv = (const float*)d_in[1];
    const float* b_qkv = (const float*)d_in[2];
    const float* w_out = (const float*)d_in[3];
    const float* b_out = (const float*)d_in[4];
    float* out = (float*)d_out;

    char* ws = (char*)d_ws;
    const size_t TAB   = (size_t)N_ * HALF * sizeof(float);      // 256 KB each
    const size_t HARR  = (size_t)B_ * H_ * N_ * HD * 2;          // 8 MB bf16 each
    float* cos_t = (float*)ws;
    float* sin_t = (float*)(ws + TAB);
    __hip_bfloat16* qf = (__hip_bfloat16*)(ws + 2 * TAB);
    __hip_bfloat16* kf = (__hip_bfloat16*)(ws + 2 * TAB + 1 * HARR);
    __hip_bfloat16* rq = (__hip_bfloat16*)(ws + 2 * TAB + 2 * HARR);
    __hip_bfloat16* rk = (__hip_bfloat16*)(ws + 2 * TAB + 3 * HARR);
    __hip_bfloat16* vt = (__hip_bfloat16*)(ws + 2 * TAB + 4 * HARR);
    float* ctx = (float*)(ws + 2 * TAB + 5 * HARR);              // 16 MB fp32

    hipLaunchKernelGGL(k_tables, dim3((N_ * HALF + 255) / 256), dim3(256), 0, stream,
                       cos_t, sin_t);
    hipLaunchKernelGGL(k_qkv, dim3(DQKV / 64, M_ / 64), dim3(256), 0, stream,
                       x, w_qkv, b_qkv, cos_t, sin_t, qf, kf, rq, rk, vt);
    hipLaunchKernelGGL(k_attn, dim3(N_ / 64 * B_ * H_), dim3(256), 0, stream,
                       qf, kf, rq, rk, vt, ctx);
    hipLaunchKernelGGL(k_proj, dim3(D_ / 64, M_ / 64), dim3(256), 0, stream,
                       ctx, w_out, b_out, out);
}

// Round 3
// 206.594 us; speedup vs baseline: 8.4792x; 2.7441x over previous
//
#include <hip/hip_runtime.h>
#include <hip/hip_bf16.h>

#define B_   2
#define N_   2048
#define D_   1024
#define H_   16
#define HD   64
#define HALF 32
#define M_   (B_*N_)     // 4096
#define DQKV (3*D_)      // 3072

typedef __bf16 bf16x8 __attribute__((ext_vector_type(8)));
typedef float  f32x4  __attribute__((ext_vector_type(4)));

// ---------------------------------------------------------------- swizzled LDS tile helpers
// tile: R rows x 64 bf16 (128B = 8 chunks of 16B per row)
// element (row, col): byte = row*128 + ((col>>3) ^ (row&7))*16 + (col&7)*2
__device__ __forceinline__ bf16x8 ldfrag(const char* tile, int row, int ch) {
    return *(const bf16x8*)(tile + row * 128 + (((ch) ^ (row & 7)) << 4));
}
__device__ __forceinline__ void stfrag16(char* tile, int row, int ch, uint4 v) {
    *(uint4*)(tile + row * 128 + (((ch) ^ (row & 7)) << 4)) = v;
}

// ---------------------------------------------------------------- K0: rope tables
__global__ __launch_bounds__(256) void k_tables(float* __restrict__ cos_t,
                                                float* __restrict__ sin_t) {
    int i = blockIdx.x * 256 + threadIdx.x;          // N_*HALF = 65536
    if (i >= N_ * HALF) return;
    int n = i / HALF, j = i % HALF;
    float theta = powf(10000.f, -(float)j / (float)HALF);
    float ang = (float)n * theta;
    cos_t[i] = cosf(ang);
    sin_t[i] = sinf(ang);
}

// ---------------------------------------------------------------- converts
__global__ __launch_bounds__(256) void k_cvt_x(const float* __restrict__ x,
                                               __hip_bfloat16* __restrict__ xb) {
    int i = blockIdx.x * 256 + threadIdx.x;          // over elems/4
    float4 v = ((const float4*)x)[i];
    union { ushort4 u; __hip_bfloat16 h[4]; } o;
    o.h[0] = __float2bfloat16(v.x); o.h[1] = __float2bfloat16(v.y);
    o.h[2] = __float2bfloat16(v.z); o.h[3] = __float2bfloat16(v.w);
    ((ushort4*)xb)[i] = o.u;
}

// transpose+convert: w (1024 x ncols, fp32) -> wt (ncols x 1024, bf16)
__global__ __launch_bounds__(256) void k_cvt_t(const float* __restrict__ w,
                                               __hip_bfloat16* __restrict__ wt, int ncols) {
    __shared__ float tile[32][33];
    int n0 = blockIdx.x * 32, k0 = blockIdx.y * 32;
    int tx = threadIdx.x & 31, ty = threadIdx.x >> 5;   // ty 0..7
#pragma unroll
    for (int i = 0; i < 32; i += 8)
        tile[ty + i][tx] = w[(size_t)(k0 + ty + i) * ncols + n0 + tx];
    __syncthreads();
#pragma unroll
    for (int i = 0; i < 32; i += 8)
        wt[(size_t)(n0 + ty + i) * 1024 + k0 + tx] = __float2bfloat16(tile[tx][ty + i]);
}

// ---------------------------------------------------------------- K1: QKV GEMM (MFMA) + elu+1 + rope
// A = xb (4096x1024 bf16 row-major), B = wqT (3072x1024 bf16, N x K)
// 128x128 tile, BK=64, 4 waves 2x2, each wave 64x64 (4x4 16x16 frags)
__global__ __launch_bounds__(256) void k_qkv(
        const __hip_bfloat16* __restrict__ xb, const __hip_bfloat16* __restrict__ wqT,
        const float* __restrict__ bias,
        const float* __restrict__ cos_t, const float* __restrict__ sin_t,
        __hip_bfloat16* __restrict__ qf, __hip_bfloat16* __restrict__ kf,
        __hip_bfloat16* __restrict__ rq, __hip_bfloat16* __restrict__ rk,
        __hip_bfloat16* __restrict__ vt) {
    __shared__ __align__(16) char sA[128 * 128];   // 128 rows x 64 bf16
    __shared__ __align__(16) char sB[128 * 128];

    const int t    = threadIdx.x;
    const int m0   = blockIdx.y * 128;
    const int n0w  = blockIdx.x * 128;
    const int lane = t & 63;
    const int lrow = lane & 15;
    const int lgrp = lane >> 4;
    const int wid  = t >> 6;
    const int wr   = wid >> 1;          // wave row 0..1
    const int wc   = wid & 1;           // wave col 0..1

    f32x4 acc[4][4] = {};

    for (int kt = 0; kt < D_ / 64; ++kt) {
        const int k0 = kt * 64;
        __syncthreads();
        // stage A,B: linear global read, swizzled LDS store
#pragma unroll
        for (int it = 0; it < 4; ++it) {
            int slot = it * 256 + t;           // 0..1023
            int r = slot >> 3, c = slot & 7;
            uint4 av = *(const uint4*)(xb  + (size_t)(m0  + r) * D_ + k0 + c * 8);
            uint4 bv = *(const uint4*)(wqT + (size_t)(n0w + r) * D_ + k0 + c * 8);
            stfrag16(sA, r, c, av);
            stfrag16(sB, r, c, bv);
        }
        __syncthreads();

        bf16x8 bfr[4][2];
#pragma unroll
        for (int fn = 0; fn < 4; ++fn) {
            bfr[fn][0] = ldfrag(sB, wc * 64 + fn * 16 + lrow, lgrp);
            bfr[fn][1] = ldfrag(sB, wc * 64 + fn * 16 + lrow, 4 + lgrp);
        }
#pragma unroll
        for (int fm = 0; fm < 4; ++fm) {
            bf16x8 a0 = ldfrag(sA, wr * 64 + fm * 16 + lrow, lgrp);
            bf16x8 a1 = ldfrag(sA, wr * 64 + fm * 16 + lrow, 4 + lgrp);
#pragma unroll
            for (int fn = 0; fn < 4; ++fn) {
                acc[fm][fn] = __builtin_amdgcn_mfma_f32_16x16x32_bf16(a0, bfr[fn][0], acc[fm][fn], 0, 0, 0);
                acc[fm][fn] = __builtin_amdgcn_mfma_f32_16x16x32_bf16(a1, bfr[fn][1], acc[fm][fn], 0, 0, 0);
            }
        }
    }

    // epilogue: bias -> (elu+1, rope) or v-scatter. sec/h/dd wave-uniform per fn except lrow.
#pragma unroll
    for (int fn = 0; fn < 4; ++fn) {
        int c   = n0w + wc * 64 + fn * 16 + lrow;
        int sec = c >> 10;                  // block-uniform (128 | 1024)
        int cc  = c & 1023;
        int h   = cc >> 6, dd = cc & 63;
        float bia = bias[c];
#pragma unroll
        for (int fm = 0; fm < 4; ++fm) {
            int mb = m0 + wr * 64 + fm * 16 + lgrp * 4;
            int b  = mb >> 11;
            int n  = mb & (N_ - 1);         // consecutive for r=0..3
            if (sec == 2) {
                union { ushort4 u; __hip_bfloat16 hh[4]; } pk;
#pragma unroll
                for (int r = 0; r < 4; ++r)
                    pk.hh[r] = __float2bfloat16(acc[fm][fn][r] + bia);
                *(ushort4*)(vt + ((size_t)(b * H_ + h) * HD + dd) * N_ + n) = pk.u;
            } else {
#pragma unroll
                for (int r = 0; r < 4; ++r) {
                    float val = acc[fm][fn][r] + bia;
                    float e  = val > 0.f ? val + 1.f : __expf(val);   // elu(x)+1
                    float ep = __shfl_xor(e, 1);
                    int pj = dd >> 1;
                    float cs = cos_t[(n + r) * HALF + pj];
                    float sn = sin_t[(n + r) * HALF + pj];
                    float rv = (dd & 1) ? (ep * sn + e * cs) : (e * cs - ep * sn);
                    size_t o = ((size_t)(b * H_ + h) * N_ + n + r) * HD + dd;
                    if (sec == 0) { qf[o] = __float2bfloat16(e); rq[o] = __float2bfloat16(rv); }
                    else          { kf[o] = __float2bfloat16(e); rk[o] = __float2bfloat16(rv); }
                }
            }
        }
    }
}

// ---------------------------------------------------------------- K2: fused linear attention (MFMA)
__global__ __launch_bounds__(256) void k_attn(
        const __hip_bfloat16* __restrict__ qf, const __hip_bfloat16* __restrict__ kf,
        const __hip_bfloat16* __restrict__ rq, const __hip_bfloat16* __restrict__ rk,
        const __hip_bfloat16* __restrict__ vt, __hip_bfloat16* __restrict__ ctxb) {
    __shared__ __align__(16) char sRq[8192];
    __shared__ __align__(16) char sQe[8192];
    __shared__ __align__(16) char sRk[8192];
    __shared__ __align__(16) char sKe[8192];
    __shared__ __align__(16) char sVt[8192];   // rows = dv, cols = k
    __shared__ __align__(16) char sW [8192];   // rows = q,  cols = k (wave-private slices)

    const int t = threadIdx.x;
    const int bid = blockIdx.x;
    const int swz = (bid & 7) * 128 + (bid >> 3);
    const int bh = swz >> 5;          // 0..31
    const int q0 = (swz & 31) * 64;
    const size_t base  = (size_t)bh * (N_ * HD);

    const int lane = t & 63;
    const int lrow = lane & 15;
    const int lgrp = lane >> 4;
    const int wid  = t >> 6;
    const int wq0  = wid * 16;

    {
        const uint4* gr = (const uint4*)(rq + base + (size_t)q0 * HD);
        const uint4* ge = (const uint4*)(qf + base + (size_t)q0 * HD);
        for (int c = t; c < 512; c += 256) {
            int row = c >> 3, ch = c & 7;
            stfrag16(sRq, row, ch, gr[c]);
            stfrag16(sQe, row, ch, ge[c]);
        }
    }
    __syncthreads();

    const bf16x8 aqr0 = ldfrag(sRq, wq0 + lrow, lgrp);
    const bf16x8 aqr1 = ldfrag(sRq, wq0 + lrow, 4 + lgrp);
    const bf16x8 aqe0 = ldfrag(sQe, wq0 + lrow, lgrp);
    const bf16x8 aqe1 = ldfrag(sQe, wq0 + lrow, 4 + lgrp);

    f32x4 o[4] = {{0,0,0,0},{0,0,0,0},{0,0,0,0},{0,0,0,0}};

    for (int kt = 0; kt < 32; ++kt) {
        const int k0 = kt * 64;
        __syncthreads();
        {
            const uint4* gr = (const uint4*)(rk + base + (size_t)k0 * HD);
            const uint4* ge = (const uint4*)(kf + base + (size_t)k0 * HD);
            const __hip_bfloat16* gv = vt + base + k0;   // row stride N_
            for (int c = t; c < 512; c += 256) {
                int row = c >> 3, ch = c & 7;
                stfrag16(sRk, row, ch, gr[c]);
                stfrag16(sKe, row, ch, ge[c]);
                uint4 vv = *(const uint4*)(gv + (size_t)row * N_ + ch * 8);
                stfrag16(sVt, row, ch, vv);
            }
        }
        __syncthreads();

#pragma unroll
        for (int c = 0; c < 4; ++c) {
            f32x4 num = {0,0,0,0}, den = {0,0,0,0};
            bf16x8 brk0 = ldfrag(sRk, c * 16 + lrow, lgrp);
            bf16x8 brk1 = ldfrag(sRk, c * 16 + lrow, 4 + lgrp);
            bf16x8 bke0 = ldfrag(sKe, c * 16 + lrow, lgrp);
            bf16x8 bke1 = ldfrag(sKe, c * 16 + lrow, 4 + lgrp);
            num = __builtin_amdgcn_mfma_f32_16x16x32_bf16(aqr0, brk0, num, 0, 0, 0);
            num = __builtin_amdgcn_mfma_f32_16x16x32_bf16(aqr1, brk1, num, 0, 0, 0);
            den = __builtin_amdgcn_mfma_f32_16x16x32_bf16(aqe0, bke0, den, 0, 0, 0);
            den = __builtin_amdgcn_mfma_f32_16x16x32_bf16(aqe1, bke1, den, 0, 0, 0);
#pragma unroll
            for (int r = 0; r < 4; ++r) {
                float wv = num[r] * __builtin_amdgcn_rcpf(den[r]);
                int row = wq0 + lgrp * 4 + r;
                int col = c * 16 + lrow;
                *(__hip_bfloat16*)(sW + row * 128 + (((col >> 3) ^ (row & 7)) << 4)
                                   + (col & 7) * 2) = __float2bfloat16(wv);
            }
        }

        bf16x8 aw0 = ldfrag(sW, wq0 + lrow, lgrp);
        bf16x8 aw1 = ldfrag(sW, wq0 + lrow, 4 + lgrp);
#pragma unroll
        for (int f = 0; f < 4; ++f) {
            bf16x8 bv0 = ldfrag(sVt, f * 16 + lrow, lgrp);
            bf16x8 bv1 = ldfrag(sVt, f * 16 + lrow, 4 + lgrp);
            o[f] = __builtin_amdgcn_mfma_f32_16x16x32_bf16(aw0, bv0, o[f], 0, 0, 0);
            o[f] = __builtin_amdgcn_mfma_f32_16x16x32_bf16(aw1, bv1, o[f], 0, 0, 0);
        }
    }

#pragma unroll
    for (int f = 0; f < 4; ++f)
#pragma unroll
        for (int r = 0; r < 4; ++r)
            ctxb[base + (size_t)(q0 + wq0 + lgrp * 4 + r) * HD + f * 16 + lrow] =
                __float2bfloat16(o[f][r]);
}

// ---------------------------------------------------------------- K3: out projection (MFMA)
// A = ctxb (B,H,N,64) bf16 (logical 4096 x 1024, k = h*64+dd), B = woT (1024x1024 bf16 NxK)
__global__ __launch_bounds__(256) void k_proj(
        const __hip_bfloat16* __restrict__ ctxb, const __hip_bfloat16* __restrict__ woT,
        const float* __restrict__ bias, float* __restrict__ out) {
    __shared__ __align__(16) char sA[128 * 128];
    __shared__ __align__(16) char sB[128 * 128];

    const int t    = threadIdx.x;
    const int m0   = blockIdx.y * 128;
    const int n0w  = blockIdx.x * 128;
    const int lane = t & 63;
    const int lrow = lane & 15;
    const int lgrp = lane >> 4;
    const int wid  = t >> 6;
    const int wr   = wid >> 1;
    const int wc   = wid & 1;

    f32x4 acc[4][4] = {};

    for (int kt = 0; kt < D_ / 64; ++kt) {
        const int k0 = kt * 64;
        const int h  = k0 >> 6;             // head for this K-step
        __syncthreads();
#pragma unroll
        for (int it = 0; it < 4; ++it) {
            int slot = it * 256 + t;
            int r = slot >> 3, c = slot & 7;
            int m = m0 + r;
            int b = m >> 11, n = m & (N_ - 1);
            uint4 av = *(const uint4*)(ctxb + ((size_t)(b * H_ + h) * N_ + n) * HD + c * 8);
            uint4 bv = *(const uint4*)(woT + (size_t)(n0w + r) * D_ + k0 + c * 8);
            stfrag16(sA, r, c, av);
            stfrag16(sB, r, c, bv);
        }
        __syncthreads();

        bf16x8 bfr[4][2];
#pragma unroll
        for (int fn = 0; fn < 4; ++fn) {
            bfr[fn][0] = ldfrag(sB, wc * 64 + fn * 16 + lrow, lgrp);
            bfr[fn][1] = ldfrag(sB, wc * 64 + fn * 16 + lrow, 4 + lgrp);
        }
#pragma unroll
        for (int fm = 0; fm < 4; ++fm) {
            bf16x8 a0 = ldfrag(sA, wr * 64 + fm * 16 + lrow, lgrp);
            bf16x8 a1 = ldfrag(sA, wr * 64 + fm * 16 + lrow, 4 + lgrp);
#pragma unroll
            for (int fn = 0; fn < 4; ++fn) {
                acc[fm][fn] = __builtin_amdgcn_mfma_f32_16x16x32_bf16(a0, bfr[fn][0], acc[fm][fn], 0, 0, 0);
                acc[fm][fn] = __builtin_amdgcn_mfma_f32_16x16x32_bf16(a1, bfr[fn][1], acc[fm][fn], 0, 0, 0);
            }
        }
    }

#pragma unroll
    for (int fn = 0; fn < 4; ++fn) {
        int c = n0w + wc * 64 + fn * 16 + lrow;
        float bia = bias[c];
#pragma unroll
        for (int fm = 0; fm < 4; ++fm) {
            int m = m0 + wr * 64 + fm * 16 + lgrp * 4;
#pragma unroll
            for (int r = 0; r < 4; ++r)
                out[(size_t)(m + r) * D_ + c] = acc[fm][fn][r] + bia;
        }
    }
}

// ---------------------------------------------------------------- launch
extern "C" void kernel_launch(void* const* d_in, const int* in_sizes, int n_in,
                              void* d_out, int out_size, void* d_ws, size_t ws_size,
                              hipStream_t stream) {
    const float* x     = (const float*)d_in[0];
    const float* w_qkv = (const float*)d_in[1];
    const float* b_qkv = (const float*)d_in[2];
    const float* w_out = (const float*)d_in[3];
    const float* b_out = (const float*)d_in[4];
    float* out = (float*)d_out;

    char* ws = (char*)d_ws;
    const size_t TAB  = (size_t)N_ * HALF * sizeof(float);      // 256 KB each
    const size_t HARR = (size_t)B_ * H_ * N_ * HD * 2;          // 8 MB bf16 each
    float* cos_t = (float*)ws;
    float* sin_t = (float*)(ws + TAB);
    char* p = ws + 2 * TAB;
    __hip_bfloat16* qf  = (__hip_bfloat16*)(p);            p += HARR;
    __hip_bfloat16* kf  = (__hip_bfloat16*)(p);            p += HARR;
    __hip_bfloat16* rq  = (__hip_bfloat16*)(p);            p += HARR;
    __hip_bfloat16* rk  = (__hip_bfloat16*)(p);            p += HARR;
    __hip_bfloat16* vt  = (__hip_bfloat16*)(p);            p += HARR;
    __hip_bfloat16* xb  = (__hip_bfloat16*)(p);            p += HARR;   // M_*D_ bf16 (8MB)
    __hip_bfloat16* ctxb = xb;      // ctx aliases xb (xb dead after k_qkv)
    __hip_bfloat16* wqT = (__hip_bfloat16*)(p);            p += (size_t)DQKV * D_ * 2;  // 6MB
    __hip_bfloat16* woT = (__hip_bfloat16*)(p);            p += (size_t)D_ * D_ * 2;    // 2MB

    hipLaunchKernelGGL(k_tables, dim3((N_ * HALF + 255) / 256), dim3(256), 0, stream,
                       cos_t, sin_t);
    hipLaunchKernelGGL(k_cvt_x, dim3(M_ * D_ / 4 / 256), dim3(256), 0, stream, x, xb);
    hipLaunchKernelGGL(k_cvt_t, dim3(DQKV / 32, D_ / 32), dim3(256), 0, stream,
                       w_qkv, wqT, DQKV);
    hipLaunchKernelGGL(k_cvt_t, dim3(D_ / 32, D_ / 32), dim3(256), 0, stream,
                       w_out, woT, D_);
    hipLaunchKernelGGL(k_qkv, dim3(DQKV / 128, M_ / 128), dim3(256), 0, stream,
                       xb, wqT, b_qkv, cos_t, sin_t, qf, kf, rq, rk, vt);
    hipLaunchKernelGGL(k_attn, dim3(N_ / 64 * B_ * H_), dim3(256), 0, stream,
                       qf, kf, rq, rk, vt, ctxb);
    hipLaunchKernelGGL(k_proj, dim3(D_ / 128, M_ / 128), dim3(256), 0, stream,
                       ctxb, woT, b_out, out);
}

// Round 4
// 188.484 us; speedup vs baseline: 9.2939x; 1.0961x over previous
//
#include <hip/hip_runtime.h>
#include <hip/hip_bf16.h>

#define B_   2
#define N_   2048
#define D_   1024
#define H_   16
#define HD   64
#define HALF 32
#define M_   (B_*N_)     // 4096
#define DQKV (3*D_)      // 3072

typedef __bf16 bf16x8 __attribute__((ext_vector_type(8)));
typedef float  f32x4  __attribute__((ext_vector_type(4)));
typedef float  f32x16 __attribute__((ext_vector_type(16)));

// ---------------------------------------------------------------- swizzled LDS tile helpers
// tile: R rows x 64 bf16 (128B = 8 chunks of 16B per row)
// element (row, col): byte = row*128 + ((col>>3) ^ (row&7))*16 + (col&7)*2
__device__ __forceinline__ bf16x8 ldfrag(const char* tile, int row, int ch) {
    return *(const bf16x8*)(tile + row * 128 + (((ch) ^ (row & 7)) << 4));
}
__device__ __forceinline__ void stfrag16(char* tile, int row, int ch, uint4 v) {
    *(uint4*)(tile + row * 128 + (((ch) ^ (row & 7)) << 4)) = v;
}

__device__ __forceinline__ unsigned pack2(float a, float b) {
    union { __hip_bfloat16 h; unsigned short s; } x, y;
    x.h = __float2bfloat16(a); y.h = __float2bfloat16(b);
    return (unsigned)x.s | ((unsigned)y.s << 16);
}

// ---------------------------------------------------------------- K0: rope tables
__global__ __launch_bounds__(256) void k_tables(float* __restrict__ cos_t,
                                                float* __restrict__ sin_t) {
    int i = blockIdx.x * 256 + threadIdx.x;          // N_*HALF = 65536
    if (i >= N_ * HALF) return;
    int n = i / HALF, j = i % HALF;
    float theta = powf(10000.f, -(float)j / (float)HALF);
    float ang = (float)n * theta;
    cos_t[i] = cosf(ang);
    sin_t[i] = sinf(ang);
}

// ---------------------------------------------------------------- converts
__global__ __launch_bounds__(256) void k_cvt_x(const float* __restrict__ x,
                                               __hip_bfloat16* __restrict__ xb) {
    int i = blockIdx.x * 256 + threadIdx.x;          // over elems/4
    float4 v = ((const float4*)x)[i];
    union { ushort4 u; __hip_bfloat16 h[4]; } o;
    o.h[0] = __float2bfloat16(v.x); o.h[1] = __float2bfloat16(v.y);
    o.h[2] = __float2bfloat16(v.z); o.h[3] = __float2bfloat16(v.w);
    ((ushort4*)xb)[i] = o.u;
}

// transpose+convert: w (1024 x ncols, fp32) -> wt (ncols x 1024, bf16)
__global__ __launch_bounds__(256) void k_cvt_t(const float* __restrict__ w,
                                               __hip_bfloat16* __restrict__ wt, int ncols) {
    __shared__ float tile[32][33];
    int n0 = blockIdx.x * 32, k0 = blockIdx.y * 32;
    int tx = threadIdx.x & 31, ty = threadIdx.x >> 5;   // ty 0..7
#pragma unroll
    for (int i = 0; i < 32; i += 8)
        tile[ty + i][tx] = w[(size_t)(k0 + ty + i) * ncols + n0 + tx];
    __syncthreads();
#pragma unroll
    for (int i = 0; i < 32; i += 8)
        wt[(size_t)(n0 + ty + i) * 1024 + k0 + tx] = __float2bfloat16(tile[tx][ty + i]);
}

// ---------------------------------------------------------------- K1: QKV GEMM (MFMA) + elu+1 + rope
__global__ __launch_bounds__(256) void k_qkv(
        const __hip_bfloat16* __restrict__ xb, const __hip_bfloat16* __restrict__ wqT,
        const float* __restrict__ bias,
        const float* __restrict__ cos_t, const float* __restrict__ sin_t,
        __hip_bfloat16* __restrict__ qf, __hip_bfloat16* __restrict__ kf,
        __hip_bfloat16* __restrict__ rq, __hip_bfloat16* __restrict__ rk,
        __hip_bfloat16* __restrict__ vt) {
    __shared__ __align__(16) char sA[128 * 128];   // 128 rows x 64 bf16
    __shared__ __align__(16) char sB[128 * 128];

    const int t    = threadIdx.x;
    const int m0   = blockIdx.y * 128;
    const int n0w  = blockIdx.x * 128;
    const int lane = t & 63;
    const int lrow = lane & 15;
    const int lgrp = lane >> 4;
    const int wid  = t >> 6;
    const int wr   = wid >> 1;          // wave row 0..1
    const int wc   = wid & 1;           // wave col 0..1

    f32x4 acc[4][4] = {};

    for (int kt = 0; kt < D_ / 64; ++kt) {
        const int k0 = kt * 64;
        __syncthreads();
#pragma unroll
        for (int it = 0; it < 4; ++it) {
            int slot = it * 256 + t;           // 0..1023
            int r = slot >> 3, c = slot & 7;
            uint4 av = *(const uint4*)(xb  + (size_t)(m0  + r) * D_ + k0 + c * 8);
            uint4 bv = *(const uint4*)(wqT + (size_t)(n0w + r) * D_ + k0 + c * 8);
            stfrag16(sA, r, c, av);
            stfrag16(sB, r, c, bv);
        }
        __syncthreads();

        bf16x8 bfr[4][2];
#pragma unroll
        for (int fn = 0; fn < 4; ++fn) {
            bfr[fn][0] = ldfrag(sB, wc * 64 + fn * 16 + lrow, lgrp);
            bfr[fn][1] = ldfrag(sB, wc * 64 + fn * 16 + lrow, 4 + lgrp);
        }
#pragma unroll
        for (int fm = 0; fm < 4; ++fm) {
            bf16x8 a0 = ldfrag(sA, wr * 64 + fm * 16 + lrow, lgrp);
            bf16x8 a1 = ldfrag(sA, wr * 64 + fm * 16 + lrow, 4 + lgrp);
#pragma unroll
            for (int fn = 0; fn < 4; ++fn) {
                acc[fm][fn] = __builtin_amdgcn_mfma_f32_16x16x32_bf16(a0, bfr[fn][0], acc[fm][fn], 0, 0, 0);
                acc[fm][fn] = __builtin_amdgcn_mfma_f32_16x16x32_bf16(a1, bfr[fn][1], acc[fm][fn], 0, 0, 0);
            }
        }
    }

#pragma unroll
    for (int fn = 0; fn < 4; ++fn) {
        int c   = n0w + wc * 64 + fn * 16 + lrow;
        int sec = c >> 10;
        int cc  = c & 1023;
        int h   = cc >> 6, dd = cc & 63;
        float bia = bias[c];
#pragma unroll
        for (int fm = 0; fm < 4; ++fm) {
            int mb = m0 + wr * 64 + fm * 16 + lgrp * 4;
            int b  = mb >> 11;
            int n  = mb & (N_ - 1);
            if (sec == 2) {
                union { ushort4 u; __hip_bfloat16 hh[4]; } pk;
#pragma unroll
                for (int r = 0; r < 4; ++r)
                    pk.hh[r] = __float2bfloat16(acc[fm][fn][r] + bia);
                *(ushort4*)(vt + ((size_t)(b * H_ + h) * HD + dd) * N_ + n) = pk.u;
            } else {
#pragma unroll
                for (int r = 0; r < 4; ++r) {
                    float val = acc[fm][fn][r] + bia;
                    float e  = val > 0.f ? val + 1.f : __expf(val);   // elu(x)+1
                    float ep = __shfl_xor(e, 1);
                    int pj = dd >> 1;
                    float cs = cos_t[(n + r) * HALF + pj];
                    float sn = sin_t[(n + r) * HALF + pj];
                    float rv = (dd & 1) ? (ep * sn + e * cs) : (e * cs - ep * sn);
                    size_t o = ((size_t)(b * H_ + h) * N_ + n + r) * HD + dd;
                    if (sec == 0) { qf[o] = __float2bfloat16(e); rq[o] = __float2bfloat16(rv); }
                    else          { kf[o] = __float2bfloat16(e); rk[o] = __float2bfloat16(rv); }
                }
            }
        }
    }
}

// ---------------------------------------------------------------- K2: fused linear attention
// Swapped-operand MFMA (32x32x16): D[k][q] = K-side x Q-side; Q-side B-frags hoisted
// in registers; W = num*rcp(den) transformed in-register (permlane32_swap) into PV
// A-frags. 4 waves x 64 q-cols = QBLK 256. Double-buffered reg staging, 1 barrier/ktile.
__global__ __launch_bounds__(256, 1) void k_attn(
        const __hip_bfloat16* __restrict__ qf, const __hip_bfloat16* __restrict__ kf,
        const __hip_bfloat16* __restrict__ rq, const __hip_bfloat16* __restrict__ rk,
        const __hip_bfloat16* __restrict__ vt, __hip_bfloat16* __restrict__ ctxb) {
    __shared__ __align__(16) char sbuf[2][3 * 8192];   // per buf: RK | KF | VT tiles

    const int t    = threadIdx.x;
    const int lane = t & 63;
    const int l31  = lane & 31;
    const int h    = lane >> 5;
    const int w    = t >> 6;

    // XCD-chunked swizzle: 256 blocks; XCD x gets bh 4x..4x+3 (K/V L2-resident)
    const int bid = blockIdx.x;
    const int swz = (bid & 7) * 32 + (bid >> 3);
    const int bh  = swz >> 3;          // 0..31
    const int q0  = (swz & 7) * 256;   // q-block base
    const size_t base = (size_t)bh * (N_ * HD);
    const int q0w = q0 + w * 64;       // this wave's 64 q-rows

    // ---- hoist Q-side B-frags (loop-invariant): B[hd][q], lane: q=l31, hd=kc*16+h*8
    bf16x8 bq[2][4], bqe[2][4];
#pragma unroll
    for (int qb = 0; qb < 2; ++qb)
#pragma unroll
        for (int kc = 0; kc < 4; ++kc) {
            int row = q0w + qb * 32 + l31;
            int col = kc * 16 + h * 8;
            bq [qb][kc] = *(const bf16x8*)(rq + base + (size_t)row * HD + col);
            bqe[qb][kc] = *(const bf16x8*)(qf + base + (size_t)row * HD + col);
        }

    // ---- staging helpers (6 x 16B per thread per ktile; pre-swizzled source chunk)
    uint4 st[6];
    {   // prologue: stage ktile 0
#pragma unroll
        for (int it = 0; it < 6; ++it) {
            int slot = it * 256 + t, ci = slot & 511, row = ci >> 3, cs = ci & 7;
            int cg = cs ^ (row & 7);
            const char* g;
            if (it < 2)      g = (const char*)(rk + base + (size_t)row * HD) + cg * 16;
            else if (it < 4) g = (const char*)(kf + base + (size_t)row * HD) + cg * 16;
            else             g = (const char*)(vt + base + (size_t)row * N_) + cg * 16;
            st[it] = *(const uint4*)g;
        }
#pragma unroll
        for (int it = 0; it < 6; ++it) {
            int slot = it * 256 + t, ci = slot & 511, row = ci >> 3, cs = ci & 7;
            *(uint4*)(sbuf[0] + (it >> 1) * 8192 + row * 128 + cs * 16) = st[it];
        }
    }
    __syncthreads();

    f32x16 o[2][2] = {};

    for (int kt = 0; kt < 32; ++kt) {
        const int cur = kt & 1;
        const char* Rk = sbuf[cur];
        const char* Ke = sbuf[cur] + 8192;
        const char* Vt = sbuf[cur] + 16384;

        // issue next tile's global loads early (latency hides under compute)
        if (kt + 1 < 32) {
            const int k0n = (kt + 1) * 64;
#pragma unroll
            for (int it = 0; it < 6; ++it) {
                int slot = it * 256 + t, ci = slot & 511, row = ci >> 3, cs = ci & 7;
                int cg = cs ^ (row & 7);
                const char* g;
                if (it < 2)      g = (const char*)(rk + base + (size_t)(k0n + row) * HD) + cg * 16;
                else if (it < 4) g = (const char*)(kf + base + (size_t)(k0n + row) * HD) + cg * 16;
                else             g = (const char*)(vt + base + (size_t)row * N_ + k0n) + cg * 16;
                st[it] = *(const uint4*)g;
            }
        }

        // ---- QK^T (swapped) + in-register W transform
        bf16x8 wa[2][4];
#pragma unroll
        for (int qb = 0; qb < 2; ++qb) {
#pragma unroll
            for (int kb = 0; kb < 2; ++kb) {
                f32x16 num = {}, den = {};
#pragma unroll
                for (int kc = 0; kc < 4; ++kc) {
                    bf16x8 ark = ldfrag(Rk, kb * 32 + l31, kc * 2 + h);
                    num = __builtin_amdgcn_mfma_f32_32x32x16_bf16(ark, bq[qb][kc], num, 0, 0, 0);
                }
#pragma unroll
                for (int kc = 0; kc < 4; ++kc) {
                    bf16x8 ake = ldfrag(Ke, kb * 32 + l31, kc * 2 + h);
                    den = __builtin_amdgcn_mfma_f32_32x32x16_bf16(ake, bqe[qb][kc], den, 0, 0, 0);
                }
                // w = num/den; lane holds W^T[k_local][q=l31], k_local = (r&3)+8*(r>>2)+4*h
                unsigned u0 = pack2(num[0]  * __builtin_amdgcn_rcpf(den[0]),
                                    num[1]  * __builtin_amdgcn_rcpf(den[1]));
                unsigned u1 = pack2(num[2]  * __builtin_amdgcn_rcpf(den[2]),
                                    num[3]  * __builtin_amdgcn_rcpf(den[3]));
                unsigned u2 = pack2(num[4]  * __builtin_amdgcn_rcpf(den[4]),
                                    num[5]  * __builtin_amdgcn_rcpf(den[5]));
                unsigned u3 = pack2(num[6]  * __builtin_amdgcn_rcpf(den[6]),
                                    num[7]  * __builtin_amdgcn_rcpf(den[7]));
                unsigned u4 = pack2(num[8]  * __builtin_amdgcn_rcpf(den[8]),
                                    num[9]  * __builtin_amdgcn_rcpf(den[9]));
                unsigned u5 = pack2(num[10] * __builtin_amdgcn_rcpf(den[10]),
                                    num[11] * __builtin_amdgcn_rcpf(den[11]));
                unsigned u6 = pack2(num[12] * __builtin_amdgcn_rcpf(den[12]),
                                    num[13] * __builtin_amdgcn_rcpf(den[13]));
                unsigned u7 = pack2(num[14] * __builtin_amdgcn_rcpf(den[14]),
                                    num[15] * __builtin_amdgcn_rcpf(den[15]));
                // lane l <-> l+32 exchange (same q): builds A-frags W[q][k]
                asm volatile("v_permlane32_swap_b32 %0, %1" : "+v"(u0), "+v"(u2));
                asm volatile("v_permlane32_swap_b32 %0, %1" : "+v"(u1), "+v"(u3));
                asm volatile("v_permlane32_swap_b32 %0, %1" : "+v"(u4), "+v"(u6));
                asm volatile("v_permlane32_swap_b32 %0, %1" : "+v"(u5), "+v"(u7));
                union { unsigned uu[4]; bf16x8 v; } f0, f1;
                f0.uu[0] = u0; f0.uu[1] = u1; f0.uu[2] = u2; f0.uu[3] = u3;
                f1.uu[0] = u4; f1.uu[1] = u5; f1.uu[2] = u6; f1.uu[3] = u7;
                wa[qb][kb * 2 + 0] = f0.v;
                wa[qb][kb * 2 + 1] = f1.v;
            }
        }

        // ---- PV: O[q][dv] += W @ V  (B = Vt rows dv, contiguous k)
#pragma unroll
        for (int qb = 0; qb < 2; ++qb)
#pragma unroll
            for (int db = 0; db < 2; ++db)
#pragma unroll
                for (int kc = 0; kc < 4; ++kc) {
                    bf16x8 bv = ldfrag(Vt, db * 32 + l31, kc * 2 + h);
                    o[qb][db] = __builtin_amdgcn_mfma_f32_32x32x16_bf16(wa[qb][kc], bv, o[qb][db], 0, 0, 0);
                }

        // ---- write next tile to other buffer, then single barrier
        if (kt + 1 < 32) {
#pragma unroll
            for (int it = 0; it < 6; ++it) {
                int slot = it * 256 + t, ci = slot & 511, row = ci >> 3, cs = ci & 7;
                *(uint4*)(sbuf[cur ^ 1] + (it >> 1) * 8192 + row * 128 + cs * 16) = st[it];
            }
        }
        __syncthreads();
    }

    // epilogue: D-frag row q = (r&3)+8*(r>>2)+4*h, col dv = l31
#pragma unroll
    for (int qb = 0; qb < 2; ++qb)
#pragma unroll
        for (int db = 0; db < 2; ++db)
#pragma unroll
            for (int r = 0; r < 16; ++r) {
                int qq = q0w + qb * 32 + (r & 3) + 8 * (r >> 2) + 4 * h;
                int dv = db * 32 + l31;
                ctxb[base + (size_t)qq * HD + dv] = __float2bfloat16(o[qb][db][r]);
            }
}

// ---------------------------------------------------------------- K3: out projection (MFMA)
__global__ __launch_bounds__(256) void k_proj(
        const __hip_bfloat16* __restrict__ ctxb, const __hip_bfloat16* __restrict__ woT,
        const float* __restrict__ bias, float* __restrict__ out) {
    __shared__ __align__(16) char sA[128 * 128];
    __shared__ __align__(16) char sB[128 * 128];

    const int t    = threadIdx.x;
    const int m0   = blockIdx.y * 128;
    const int n0w  = blockIdx.x * 128;
    const int lane = t & 63;
    const int lrow = lane & 15;
    const int lgrp = lane >> 4;
    const int wid  = t >> 6;
    const int wr   = wid >> 1;
    const int wc   = wid & 1;

    f32x4 acc[4][4] = {};

    for (int kt = 0; kt < D_ / 64; ++kt) {
        const int k0 = kt * 64;
        const int hh = k0 >> 6;
        __syncthreads();
#pragma unroll
        for (int it = 0; it < 4; ++it) {
            int slot = it * 256 + t;
            int r = slot >> 3, c = slot & 7;
            int m = m0 + r;
            int b = m >> 11, n = m & (N_ - 1);
            uint4 av = *(const uint4*)(ctxb + ((size_t)(b * H_ + hh) * N_ + n) * HD + c * 8);
            uint4 bv = *(const uint4*)(woT + (size_t)(n0w + r) * D_ + k0 + c * 8);
            stfrag16(sA, r, c, av);
            stfrag16(sB, r, c, bv);
        }
        __syncthreads();

        bf16x8 bfr[4][2];
#pragma unroll
        for (int fn = 0; fn < 4; ++fn) {
            bfr[fn][0] = ldfrag(sB, wc * 64 + fn * 16 + lrow, lgrp);
            bfr[fn][1] = ldfrag(sB, wc * 64 + fn * 16 + lrow, 4 + lgrp);
        }
#pragma unroll
        for (int fm = 0; fm < 4; ++fm) {
            bf16x8 a0 = ldfrag(sA, wr * 64 + fm * 16 + lrow, lgrp);
            bf16x8 a1 = ldfrag(sA, wr * 64 + fm * 16 + lrow, 4 + lgrp);
#pragma unroll
            for (int fn = 0; fn < 4; ++fn) {
                acc[fm][fn] = __builtin_amdgcn_mfma_f32_16x16x32_bf16(a0, bfr[fn][0], acc[fm][fn], 0, 0, 0);
                acc[fm][fn] = __builtin_amdgcn_mfma_f32_16x16x32_bf16(a1, bfr[fn][1], acc[fm][fn], 0, 0, 0);
            }
        }
    }

#pragma unroll
    for (int fn = 0; fn < 4; ++fn) {
        int c = n0w + wc * 64 + fn * 16 + lrow;
        float bia = bias[c];
#pragma unroll
        for (int fm = 0; fm < 4; ++fm) {
            int m = m0 + wr * 64 + fm * 16 + lgrp * 4;
#pragma unroll
            for (int r = 0; r < 4; ++r)
                out[(size_t)(m + r) * D_ + c] = acc[fm][fn][r] + bia;
        }
    }
}

// ---------------------------------------------------------------- launch
extern "C" void kernel_launch(void* const* d_in, const int* in_sizes, int n_in,
                              void* d_out, int out_size, void* d_ws, size_t ws_size,
                              hipStream_t stream) {
    const float* x     = (const float*)d_in[0];
    const float* w_qkv = (const float*)d_in[1];
    const float* b_qkv = (const float*)d_in[2];
    const float* w_out = (const float*)d_in[3];
    const float* b_out = (const float*)d_in[4];
    float* out = (float*)d_out;

    char* ws = (char*)d_ws;
    const size_t TAB  = (size_t)N_ * HALF * sizeof(float);      // 256 KB each
    const size_t HARR = (size_t)B_ * H_ * N_ * HD * 2;          // 8 MB bf16 each
    float* cos_t = (float*)ws;
    float* sin_t = (float*)(ws + TAB);
    char* p = ws + 2 * TAB;
    __hip_bfloat16* qf  = (__hip_bfloat16*)(p);            p += HARR;
    __hip_bfloat16* kf  = (__hip_bfloat16*)(p);            p += HARR;
    __hip_bfloat16* rq  = (__hip_bfloat16*)(p);            p += HARR;
    __hip_bfloat16* rk  = (__hip_bfloat16*)(p);            p += HARR;
    __hip_bfloat16* vt  = (__hip_bfloat16*)(p);            p += HARR;
    __hip_bfloat16* xb  = (__hip_bfloat16*)(p);            p += HARR;   // M_*D_ bf16 (8MB)
    __hip_bfloat16* ctxb = xb;      // ctx aliases xb (xb dead after k_qkv)
    __hip_bfloat16* wqT = (__hip_bfloat16*)(p);            p += (size_t)DQKV * D_ * 2;  // 6MB
    __hip_bfloat16* woT = (__hip_bfloat16*)(p);            p += (size_t)D_ * D_ * 2;    // 2MB

    hipLaunchKernelGGL(k_tables, dim3((N_ * HALF + 255) / 256), dim3(256), 0, stream,
                       cos_t, sin_t);
    hipLaunchKernelGGL(k_cvt_x, dim3(M_ * D_ / 4 / 256), dim3(256), 0, stream, x, xb);
    hipLaunchKernelGGL(k_cvt_t, dim3(DQKV / 32, D_ / 32), dim3(256), 0, stream,
                       w_qkv, wqT, DQKV);
    hipLaunchKernelGGL(k_cvt_t, dim3(D_ / 32, D_ / 32), dim3(256), 0, stream,
                       w_out, woT, D_);
    hipLaunchKernelGGL(k_qkv, dim3(DQKV / 128, M_ / 128), dim3(256), 0, stream,
                       xb, wqT, b_qkv, cos_t, sin_t, qf, kf, rq, rk, vt);
    hipLaunchKernelGGL(k_attn, dim3(256), dim3(256), 0, stream,
                       qf, kf, rq, rk, vt, ctxb);
    hipLaunchKernelGGL(k_proj, dim3(D_ / 128, M_ / 128), dim3(256), 0, stream,
                       ctxb, woT, b_out, out);
}